// Round 7
// baseline (2627.756 us; speedup 1.0000x reference)
//
#include <hip/hip_runtime.h>
#include <math.h>

#define B_   8
#define NIN  20000
#define NALL 1200
#define NPTQ 1024
#define KNB  34
#define CH   96
#define FF   384
#define NQ   (B_ * NPTQ)   // 8192
#define SL   20            // points per thread in FPS (20*1024 >= 20000)

typedef unsigned int   u32;
typedef unsigned long long u64;

// Fast-math-proof non-finite check (integer ops can't be folded away).
__device__ __forceinline__ float scrub(float f) {
    u32 u = __float_as_uint(f);
    return ((u & 0x7F800000u) == 0x7F800000u) ? 12345.0f : f;   // diagnostic sentinel
}

// ---------------------------------------------------------------------------
// 1. Farthest point sampling: one block per batch, 1024 threads, 20 pts/thread
//    in registers.  KEY FIX vs round 6: __launch_bounds__(1024, 4) — without
//    the ",4" the compiler targets 8 waves/EU (VGPR cap 64), which CANNOT hold
//    the 80 coord registers, so it rematerialized the global loads every
//    iteration (245 KB/iter through L1 ~= 3830 cyc, the measured 2x overhead).
//    With cap 128 + asm pinning (asm results can't be re-executed -> no remat)
//    the coords stay VGPR-resident.  One barrier/iter via double-buffered LDS;
//    centroid re-fetch is a same-address broadcast load (L2-resident).
//    Exact numpy fp32 semantics: no FMA, ((dx2+dy2)+dz2), ties -> lowest index
//    via (dist, NIN-idx) packed keys.
// ---------------------------------------------------------------------------
__global__ __launch_bounds__(1024, 4) void fps_kernel(const float* __restrict__ pc,
                                                      int* __restrict__ fps_idx) {
    const int b = blockIdx.x;
    const int tid = threadIdx.x;
    const int lane = tid & 63;
    const int wid = tid >> 6;
    const float* base = pc + (size_t)b * NIN * 3;

    float px[SL], py[SL], pz[SL], dist[SL];
#pragma unroll
    for (int j = 0; j < SL; ++j) {
        int idx = tid + j * 1024;
        bool ok = (j < SL - 1) || (idx < NIN);
        int ia = ok ? idx : 0;
        px[j] = base[(size_t)ia * 3 + 0];
        py[j] = base[(size_t)ia * 3 + 1];
        pz[j] = base[(size_t)ia * 3 + 2];
        dist[j] = ok ? 1e10f : -1.0f;   // padding can never win argmax (real >= 0)
    }
    // Pin coords into VGPRs: the empty asm makes each value's definition
    // opaque; combined with the 128-VGPR cap the compiler keeps them resident.
#pragma unroll
    for (int j = 0; j < SL; ++j) {
        asm volatile("" : "+v"(px[j]), "+v"(py[j]), "+v"(pz[j]));
    }

    __shared__ u64 red[2][16];

    if (tid == 0) fps_idx[b * NALL + 0] = 0;
    float cx = base[0], cy = base[1], cz = base[2];

    for (int it = 1; it < NALL; ++it) {
        const int p = it & 1;
        float bd = -1e38f; int bi = 0;
#pragma unroll
        for (int j = 0; j < SL; ++j) {
            float dx = __fsub_rn(px[j], cx);
            float dy = __fsub_rn(py[j], cy);
            float dz = __fsub_rn(pz[j], cz);
            float d = __fadd_rn(__fadd_rn(__fmul_rn(dx, dx), __fmul_rn(dy, dy)),
                                __fmul_rn(dz, dz));
            float nd = fminf(dist[j], d);
            dist[j] = nd;
            if (nd > bd) { bd = nd; bi = tid + j * 1024; }  // first-max kept
        }
        // key: larger dist wins; equal dist -> larger (NIN-bi) -> smaller bi
        u64 key = ((u64)__float_as_uint(bd) << 32) | (u32)(NIN - bi);
#pragma unroll
        for (int s = 32; s; s >>= 1) {
            u64 o = __shfl_xor(key, s, 64);
            key = (o > key) ? o : key;
        }
        if (lane == 0) red[p][wid] = key;
        __syncthreads();                       // single barrier per iteration
        u64 k2 = red[p][lane & 15];            // double buffer makes WAR safe
#pragma unroll
        for (int s = 1; s < 16; s <<= 1) {
            u64 o = __shfl_xor(k2, s, 64);
            k2 = (o > k2) ? o : k2;
        }
        int widx = NIN - (int)(k2 & 0xFFFFFFFFu);
        if (tid == 0) fps_idx[b * NALL + it] = widx;
        const float* wp = base + (size_t)widx * 3;
        cx = wp[0]; cy = wp[1]; cz = wp[2];    // same addr all lanes: broadcast
    }
}

// ---------------------------------------------------------------------------
// 2. Gather coords at fps_idx[sel]; fp32 coord workspace + fp32 coord output
// ---------------------------------------------------------------------------
__global__ void gather_kernel(const float* __restrict__ pc,
                              const int* __restrict__ fps_idx, const int* __restrict__ sel,
                              float* __restrict__ coord, float* __restrict__ out_coord) {
    int t = blockIdx.x * 256 + threadIdx.x;
    if (t >= NQ) return;
    int b = t >> 10, j = t & 1023;
    int p = fps_idx[b * NALL + sel[j]];
    p = (p < 0) ? 0 : ((p >= NIN) ? (NIN - 1) : p);   // defensive clamp
    const float* pp = pc + ((size_t)b * NIN + p) * 3;
    float x = pp[0], y = pp[1], z = pp[2];
    coord[(size_t)t * 3 + 0] = x;
    coord[(size_t)t * 3 + 1] = y;
    coord[(size_t)t * 3 + 2] = z;
    out_coord[(size_t)t * 3 + 0] = scrub(x);
    out_coord[(size_t)t * 3 + 1] = scrub(y);
    out_coord[(size_t)t * 3 + 2] = scrub(z);
}

// ---------------------------------------------------------------------------
// 3. kNN within radius: one wave per query, stable (d2, idx) ascending, K=34.
// ---------------------------------------------------------------------------
__global__ void knn_kernel(const float* __restrict__ coord, int* __restrict__ nbr) {
    __shared__ float sx[NPTQ], sy[NPTQ], sz[NPTQ];
    const double RAD2D = (2.5 * 0.04) * (2.5 * 0.04);
    int b = blockIdx.x >> 8;              // 256 blocks per batch
    int i0 = (blockIdx.x & 255) * 4;
    const float* cb = coord + (size_t)b * NPTQ * 3;
    for (int t = threadIdx.x; t < NPTQ; t += 256) {
        sx[t] = cb[(size_t)t * 3 + 0];
        sy[t] = cb[(size_t)t * 3 + 1];
        sz[t] = cb[(size_t)t * 3 + 2];
    }
    __syncthreads();
    int wid = threadIdx.x >> 6, lane = threadIdx.x & 63;
    int i = i0 + wid;
    float qx = sx[i], qy = sy[i], qz = sz[i];
    u64 pk[16];
#pragma unroll
    for (int t = 0; t < 16; ++t) {
        int j = lane + t * 64;
        float dx = __fsub_rn(qx, sx[j]);
        float dy = __fsub_rn(qy, sy[j]);
        float dz = __fsub_rn(qz, sz[j]);
        float d2 = __fadd_rn(__fadd_rn(__fmul_rn(dx, dx), __fmul_rn(dy, dy)),
                             __fmul_rn(dz, dz));
        bool valid = ((double)d2 <= RAD2D);
        pk[t] = valid ? (((u64)__float_as_uint(d2) << 32) | (u32)j) : ~0ull;
    }
    int* out = nbr + ((size_t)b * NPTQ + i) * KNB;
    int k = 0;
    for (; k < KNB; ++k) {
        u64 m = ~0ull;
#pragma unroll
        for (int t = 0; t < 16; ++t) m = (pk[t] < m) ? pk[t] : m;
#pragma unroll
        for (int s = 32; s; s >>= 1) {
            u64 o = __shfl_xor(m, s, 64);
            m = (o < m) ? o : m;
        }
        if (m == ~0ull) break;
#pragma unroll
        for (int t = 0; t < 16; ++t) if (pk[t] == m) pk[t] = ~0ull;
        if (lane == 0) out[k] = (int)(m & 0xFFFFFFFFu);
    }
    for (; k < KNB; ++k) if (lane == 0) out[k] = -1;
}

// ---------------------------------------------------------------------------
// 4. x = [color, coord] @ W_in + b_in  (reads inputs directly via fps_idx/sel)
// ---------------------------------------------------------------------------
__global__ void xproj_kernel(const float* __restrict__ pc, const float* __restrict__ col,
                             const int* __restrict__ fps_idx, const int* __restrict__ sel,
                             const float* __restrict__ Win, const float* __restrict__ bin,
                             float* __restrict__ x) {
    int idx = blockIdx.x * 256 + threadIdx.x;
    if (idx >= NQ * CH) return;
    int q = idx / CH, c = idx - q * CH;
    int b = q >> 10, j = q & 1023;
    int p = fps_idx[b * NALL + sel[j]];
    p = (p < 0) ? 0 : ((p >= NIN) ? (NIN - 1) : p);
    const float* pp = pc + ((size_t)b * NIN + p) * 3;
    const float* cc = col + ((size_t)b * NIN + p) * 3;
    float acc = bin[c];
    acc += cc[0] * Win[0 * CH + c];
    acc += cc[1] * Win[1 * CH + c];
    acc += cc[2] * Win[2 * CH + c];
    acc += pp[0] * Win[3 * CH + c];
    acc += pp[1] * Win[4 * CH + c];
    acc += pp[2] * Win[5 * CH + c];
    x[idx] = acc;
}

// ---------------------------------------------------------------------------
// 5. q,k,v = x @ Wq/Wk/Wv  (computed once per point)
// ---------------------------------------------------------------------------
__global__ void qkv_kernel(const float* __restrict__ x,
                           const float* __restrict__ Wq, const float* __restrict__ Wk,
                           const float* __restrict__ Wv,
                           float* __restrict__ qo, float* __restrict__ ko,
                           float* __restrict__ vo) {
    int idx = blockIdx.x * 256 + threadIdx.x;
    if (idx >= NQ * CH) return;
    int q = idx / CH, c = idx - q * CH;
    const float* xr = x + (size_t)q * CH;
    float aq = 0.f, ak = 0.f, av = 0.f;
    for (int k = 0; k < CH; ++k) {
        float xv = xr[k];
        aq += xv * Wq[k * CH + c];
        ak += xv * Wk[k * CH + c];
        av += xv * Wv[k * CH + c];
    }
    qo[idx] = aq; ko[idx] = ak; vo[idx] = av;
}

// ---------------------------------------------------------------------------
// 6. Attention (online softmax) fused with o-projection + residual.
//    Block = 384 threads = 4 queries x 96 channels; r1 in-place over q.
// ---------------------------------------------------------------------------
__global__ __launch_bounds__(384) void attn_kernel(float* __restrict__ qr1,
                            const float* __restrict__ km, const float* __restrict__ vm,
                            const float* __restrict__ coord, const int* __restrict__ nbr,
                            const float* __restrict__ Wpos, const float* __restrict__ Wo,
                            const float* __restrict__ x) {
    __shared__ float wp[3 * CH];
    __shared__ float os[4][CH];
    for (int t = threadIdx.x; t < 3 * CH; t += 384) wp[t] = Wpos[t];
    __syncthreads();
    int lq = threadIdx.x / CH;
    int c = threadIdx.x - lq * CH;
    int qi = blockIdx.x * 4 + lq;           // global row 0..8191
    int b = qi >> 10, i = qi & 1023;
    const float* crd = coord + (size_t)b * NPTQ * 3;
    float cx = crd[(size_t)i * 3], cy = crd[(size_t)i * 3 + 1], cz = crd[(size_t)i * 3 + 2];
    float qv = qr1[(size_t)qi * CH + c];
    const int* nb = nbr + (size_t)qi * KNB;
    float m = -1e30f, l = 0.f, acc = 0.f;
    for (int t = 0; t < KNB; ++t) {
        int j = nb[t];                      // uniform across the row's 96 threads
        if (j < 0) break;                   // valid-first ordering
        float dx = cx - crd[(size_t)j * 3];
        float dy = cy - crd[(size_t)j * 3 + 1];
        float dz = cz - crd[(size_t)j * 3 + 2];
        float pe = dx * wp[c] + dy * wp[CH + c] + dz * wp[2 * CH + c];
        size_t row = (size_t)(b * NPTQ + j) * CH + c;
        float kn = km[row] + pe;
        float s = qv * kn;
        s += __shfl_xor(s, 1); s += __shfl_xor(s, 2);
        s += __shfl_xor(s, 4); s += __shfl_xor(s, 8);
        float logit = s * 0.25f;            // / sqrt(16)
        float mn = fmaxf(m, logit);
        float sc = expf(m - mn);
        float p = expf(logit - mn);
        float vn = vm[row] + pe;
        l = l * sc + p;
        acc = acc * sc + p * vn;
        m = mn;
    }
    os[lq][c] = (l > 0.f) ? acc / l : 0.f;  // self is always valid -> l >= 1
    __syncthreads();
    // r1 = x + attn_out @ Wo
    float r = x[(size_t)qi * CH + c];
    for (int k = 0; k < CH; ++k) r += os[lq][k] * Wo[k * CH + c];
    qr1[(size_t)qi * CH + c] = r;
}

// ---------------------------------------------------------------------------
// 7. LayerNorm (wave per row of 96)
// ---------------------------------------------------------------------------
__global__ void ln_kernel(const float* __restrict__ in, const float* __restrict__ g,
                          const float* __restrict__ be, float* __restrict__ out) {
    int row = blockIdx.x * 4 + (threadIdx.x >> 6);
    int lane = threadIdx.x & 63;
    const float* r = in + (size_t)row * CH;
    float e0 = r[lane];
    float e1 = (lane < 32) ? r[64 + lane] : 0.0f;
    float s = e0 + e1;
#pragma unroll
    for (int k = 32; k; k >>= 1) s += __shfl_xor(s, k);
    float mean = s * (1.0f / 96.0f);
    float d0 = e0 - mean, d1 = e1 - mean;
    float vs = d0 * d0 + ((lane < 32) ? d1 * d1 : 0.0f);
#pragma unroll
    for (int k = 32; k; k >>= 1) vs += __shfl_xor(vs, k);
    float rs = 1.0f / sqrtf(vs * (1.0f / 96.0f) + 1e-5f);
    float* o = out + (size_t)row * CH;
    o[lane] = d0 * rs * g[lane] + be[lane];
    if (lane < 32) o[64 + lane] = d1 * rs * g[64 + lane] + be[64 + lane];
}

// ---------------------------------------------------------------------------
// 8. Fused FFN, 4 rows per block (weight traffic /4):
//    r2 = x2 + relu(x2 @ W1 + b1) @ W2 + b2
// ---------------------------------------------------------------------------
__global__ __launch_bounds__(384) void ffn_kernel(const float* __restrict__ x2,
                           const float* __restrict__ W1, const float* __restrict__ b1,
                           const float* __restrict__ W2, const float* __restrict__ b2,
                           float* __restrict__ r2) {
    __shared__ float xs[4][CH];
    __shared__ float hs[4][FF];
    __shared__ float ps[4][4][CH];
    int row0 = blockIdx.x * 4, t = threadIdx.x;
    { int r = t / CH, c = t - (t / CH) * CH;
      xs[r][c] = x2[(size_t)(row0 + r) * CH + c]; }
    __syncthreads();
    {
        float bt = b1[t];
        float a0 = bt, a1 = bt, a2 = bt, a3 = bt;
        for (int k = 0; k < CH; ++k) {
            float w = W1[k * FF + t];
            a0 += xs[0][k] * w; a1 += xs[1][k] * w;
            a2 += xs[2][k] * w; a3 += xs[3][k] * w;
        }
        hs[0][t] = fmaxf(a0, 0.f); hs[1][t] = fmaxf(a1, 0.f);
        hs[2][t] = fmaxf(a2, 0.f); hs[3][t] = fmaxf(a3, 0.f);
    }
    __syncthreads();
    {
        int chunk = t / CH, c = t - (t / CH) * CH;
        float p0 = 0.f, p1 = 0.f, p2 = 0.f, p3 = 0.f;
        for (int m = chunk * CH; m < (chunk + 1) * CH; ++m) {
            float w = W2[m * CH + c];
            p0 += hs[0][m] * w; p1 += hs[1][m] * w;
            p2 += hs[2][m] * w; p3 += hs[3][m] * w;
        }
        ps[0][chunk][c] = p0; ps[1][chunk][c] = p1;
        ps[2][chunk][c] = p2; ps[3][chunk][c] = p3;
    }
    __syncthreads();
    { int r = t / CH, c = t - (t / CH) * CH;
      float rr = xs[r][c] + ((ps[r][0][c] + ps[r][1][c]) + (ps[r][2][c] + ps[r][3][c])) + b2[c];
      r2[(size_t)(row0 + r) * CH + c] = rr; }
}

// ---------------------------------------------------------------------------
// 9. LN2 + transposed fp32 store: out[b][c][i] = LN(r2)[b][i][c]
// ---------------------------------------------------------------------------
__global__ void ln2t_kernel(const float* __restrict__ in, const float* __restrict__ g,
                            const float* __restrict__ be, float* __restrict__ out) {
    int row = blockIdx.x * 4 + (threadIdx.x >> 6);
    int lane = threadIdx.x & 63;
    int b = row >> 10, i = row & 1023;
    const float* r = in + (size_t)row * CH;
    float e0 = r[lane];
    float e1 = (lane < 32) ? r[64 + lane] : 0.0f;
    float s = e0 + e1;
#pragma unroll
    for (int k = 32; k; k >>= 1) s += __shfl_xor(s, k);
    float mean = s * (1.0f / 96.0f);
    float d0 = e0 - mean, d1 = e1 - mean;
    float vs = d0 * d0 + ((lane < 32) ? d1 * d1 : 0.0f);
#pragma unroll
    for (int k = 32; k; k >>= 1) vs += __shfl_xor(vs, k);
    float rs = 1.0f / sqrtf(vs * (1.0f / 96.0f) + 1e-5f);
    float y0 = d0 * rs * g[lane] + be[lane];
    out[((size_t)(b * CH + lane)) * NPTQ + i] = scrub(y0);
    if (lane < 32) {
        float y1 = d1 * rs * g[64 + lane] + be[64 + lane];
        out[((size_t)(b * CH + 64 + lane)) * NPTQ + i] = scrub(y1);
    }
}

// ---------------------------------------------------------------------------
extern "C" void kernel_launch(void* const* d_in, const int* in_sizes, int n_in,
                              void* d_out, int out_size, void* d_ws, size_t ws_size,
                              hipStream_t stream) {
    const float* pc   = (const float*)d_in[0];
    const float* col  = (const float*)d_in[1];
    const float* Win  = (const float*)d_in[2];
    const float* bin  = (const float*)d_in[3];
    const float* Wq   = (const float*)d_in[4];
    const float* Wk   = (const float*)d_in[5];
    const float* Wv   = (const float*)d_in[6];
    const float* Wo   = (const float*)d_in[7];
    const float* Wpos = (const float*)d_in[8];
    const float* W1   = (const float*)d_in[9];
    const float* b1   = (const float*)d_in[10];
    const float* W2   = (const float*)d_in[11];
    const float* b2   = (const float*)d_in[12];
    const float* g1   = (const float*)d_in[13];
    const float* be1  = (const float*)d_in[14];
    const float* g2   = (const float*)d_in[15];
    const float* be2  = (const float*)d_in[16];
    const int*  sel   = (const int*)d_in[17];

    float* out_feat  = (float*)d_out;                      // 8*96*1024 fp32
    float* out_coord = out_feat + (size_t)B_ * CH * NPTQ;  // 8*1024*3 fp32

    // Workspace: ~13.8 MB total.
    char* ws = (char*)d_ws;
    size_t off = 0;
    auto alloc = [&](size_t bytes) { void* p = ws + off; off += (bytes + 255) & ~(size_t)255; return p; };
    int*   w_fps   = (int*)  alloc((size_t)B_ * NALL * 4);       //  38 KB
    float* w_coord = (float*)alloc((size_t)NQ * 3 * 4);          //  98 KB
    int*   w_nbr   = (int*)  alloc((size_t)NQ * KNB * 4);        // 1.1 MB
    float* w_x     = (float*)alloc((size_t)NQ * CH * 4);         // 3.1 MB
    float* w_q     = (float*)alloc((size_t)NQ * CH * 4);         // 3.1 MB (q -> r1 in-place)
    float* w_k     = (float*)alloc((size_t)NQ * CH * 4);         // 3.1 MB (k -> x2 after attn)
    float* w_v     = (float*)alloc((size_t)NQ * CH * 4);         // 3.1 MB (v -> r2 after attn)
    (void)ws_size; (void)in_sizes; (void)n_in; (void)out_size;

    fps_kernel<<<B_, 1024, 0, stream>>>(pc, w_fps);
    gather_kernel<<<NQ / 256, 256, 0, stream>>>(pc, w_fps, sel, w_coord, out_coord);
    knn_kernel<<<NQ / 4, 256, 0, stream>>>(w_coord, w_nbr);
    xproj_kernel<<<NQ * CH / 256, 256, 0, stream>>>(pc, col, w_fps, sel, Win, bin, w_x);
    qkv_kernel<<<NQ * CH / 256, 256, 0, stream>>>(w_x, Wq, Wk, Wv, w_q, w_k, w_v);
    attn_kernel<<<NQ / 4, 384, 0, stream>>>(w_q, w_k, w_v, w_coord, w_nbr, Wpos, Wo, w_x);
    ln_kernel<<<NQ / 4, 256, 0, stream>>>(w_q, g1, be1, w_k);       // r1 -> x2
    ffn_kernel<<<NQ / 4, 384, 0, stream>>>(w_k, W1, b1, W2, b2, w_v);   // x2 -> r2
    ln2t_kernel<<<NQ / 4, 256, 0, stream>>>(w_v, g2, be2, out_feat);
}

// Round 8
// 2476.679 us; speedup vs baseline: 1.0610x; 1.0610x over previous
//
#include <hip/hip_runtime.h>
#include <math.h>

#define B_   8
#define NIN  20000
#define NALL 1200
#define NPTQ 1024
#define KNB  34
#define CH   96
#define FF   384
#define NQ   (B_ * NPTQ)   // 8192

#define FT   512           // FPS threads per block
#define NPR  20            // float2 pairs per thread: 2*NPR*FT = 20480 >= 20000

typedef unsigned int   u32;
typedef unsigned long long u64;
typedef float v2f __attribute__((ext_vector_type(2)));

// Fast-math-proof non-finite check (integer ops can't be folded away).
__device__ __forceinline__ float scrub(float f) {
    u32 u = __float_as_uint(f);
    return ((u & 0x7F800000u) == 0x7F800000u) ? 12345.0f : f;   // diagnostic sentinel
}

// ---------------------------------------------------------------------------
// 1. Farthest point sampling: one block per batch, 512 threads, 40 pts/thread
//    held as 20 float2 pairs in VGPRs.
//    Round-7 lesson: loads from const __restrict__ are REMATERIALIZABLE — the
//    allocator reloads every iteration no matter the VGPR cap.  Fix: identity
//    __shfl at init (cross-lane = convergent = not remat-able) forces true
//    register residency; __launch_bounds__(512,2) gives cap 256 (need ~200).
//    float2 arithmetic lowers to v_pk_*_f32 (2 FLOP/instr).  fp contract OFF
//    keeps exact numpy fp32 semantics: sub/mul/add/add rn, no FMA.  Argmax:
//    two independent scalar chains (even/odd) merged via u64 (dist, NIN-idx)
//    keys -> ties resolve to lowest global index, first-max kept in-chain.
// ---------------------------------------------------------------------------
__global__ __launch_bounds__(FT, 2) void fps_kernel(const float* __restrict__ pc,
                                                    int* __restrict__ fps_idx) {
#pragma clang fp contract(off)
    const int b = blockIdx.x;
    const int tid = threadIdx.x;
    const int lane = tid & 63;
    const int wid = tid >> 6;          // 0..7
    const float* base = pc + (size_t)b * NIN * 3;

    v2f px[NPR], py[NPR], pz[NPR], dist[NPR];
#pragma unroll
    for (int j = 0; j < NPR; ++j) {
        int i0 = tid + (2 * j) * FT;   // max 19967: always valid
        int i1 = i0 + FT;              // max 20479: padded when >= NIN
        bool ok1 = i1 < NIN;
        int a1 = ok1 ? i1 : 0;
        float x0 = base[(size_t)i0 * 3 + 0];
        float y0 = base[(size_t)i0 * 3 + 1];
        float z0 = base[(size_t)i0 * 3 + 2];
        float x1 = base[(size_t)a1 * 3 + 0];
        float y1 = base[(size_t)a1 * 3 + 1];
        float z1 = base[(size_t)a1 * 3 + 2];
        // identity shuffle: cross-lane op -> result cannot be rematerialized
        x0 = __shfl(x0, lane); y0 = __shfl(y0, lane); z0 = __shfl(z0, lane);
        x1 = __shfl(x1, lane); y1 = __shfl(y1, lane); z1 = __shfl(z1, lane);
        px[j].x = x0; px[j].y = x1;
        py[j].x = y0; py[j].y = y1;
        pz[j].x = z0; pz[j].y = z1;
        dist[j].x = 1e10f;
        dist[j].y = ok1 ? 1e10f : -1.0f;   // padding can never win (real >= 0)
    }

    __shared__ u64 rkey[2][8];

    if (tid == 0) fps_idx[b * NALL + 0] = 0;
    float cx = base[0], cy = base[1], cz = base[2];

    for (int it = 1; it < NALL; ++it) {
        const int pb = it & 1;
        v2f cvx; cvx.x = cx; cvx.y = cx;
        v2f cvy; cvy.x = cy; cvy.y = cy;
        v2f cvz; cvz.x = cz; cvz.y = cz;
        float bd0 = -1e38f, bd1 = -1e38f;
        int bi0 = 0, bi1 = 0;
#pragma unroll
        for (int j = 0; j < NPR; ++j) {
            v2f dx = px[j] - cvx;
            v2f dy = py[j] - cvy;
            v2f dz = pz[j] - cvz;
            v2f sx = dx * dx;
            v2f sy = dy * dy;
            v2f sz = dz * dz;
            v2f d  = (sx + sy) + sz;          // exact numpy order, no FMA
            v2f nd = __builtin_elementwise_min(dist[j], d);
            dist[j] = nd;
            if (nd.x > bd0) { bd0 = nd.x; bi0 = tid + (2 * j) * FT; }
            if (nd.y > bd1) { bd1 = nd.y; bi1 = tid + (2 * j + 1) * FT; }
        }
        // merge the two chains with exact tie semantics (lower index wins)
        u64 k0 = ((u64)__float_as_uint(bd0) << 32) | (u32)(NIN - bi0);
        u64 k1 = ((u64)__float_as_uint(bd1) << 32) | (u32)(NIN - bi1);
        u64 key = (k1 > k0) ? k1 : k0;
#pragma unroll
        for (int s = 32; s; s >>= 1) {
            u64 o = __shfl_xor(key, s, 64);
            key = (o > key) ? o : key;
        }
        if (lane == 0) rkey[pb][wid] = key;
        __syncthreads();                      // single barrier per iteration
        u64 kk = rkey[pb][0];                 // broadcast reads, WAR-safe (dbuf)
#pragma unroll
        for (int w = 1; w < 8; ++w) { u64 o = rkey[pb][w]; kk = (o > kk) ? o : kk; }
        int widx = NIN - (int)(kk & 0xFFFFFFFFu);
        if (tid == 0) fps_idx[b * NALL + it] = widx;
        const float* wp = base + (size_t)widx * 3;
        cx = wp[0]; cy = wp[1]; cz = wp[2];   // same addr all lanes: broadcast
    }
}

// ---------------------------------------------------------------------------
// 2. Gather coords at fps_idx[sel]; fp32 coord workspace + fp32 coord output
// ---------------------------------------------------------------------------
__global__ void gather_kernel(const float* __restrict__ pc,
                              const int* __restrict__ fps_idx, const int* __restrict__ sel,
                              float* __restrict__ coord, float* __restrict__ out_coord) {
    int t = blockIdx.x * 256 + threadIdx.x;
    if (t >= NQ) return;
    int b = t >> 10, j = t & 1023;
    int p = fps_idx[b * NALL + sel[j]];
    p = (p < 0) ? 0 : ((p >= NIN) ? (NIN - 1) : p);   // defensive clamp
    const float* pp = pc + ((size_t)b * NIN + p) * 3;
    float x = pp[0], y = pp[1], z = pp[2];
    coord[(size_t)t * 3 + 0] = x;
    coord[(size_t)t * 3 + 1] = y;
    coord[(size_t)t * 3 + 2] = z;
    out_coord[(size_t)t * 3 + 0] = scrub(x);
    out_coord[(size_t)t * 3 + 1] = scrub(y);
    out_coord[(size_t)t * 3 + 2] = scrub(z);
}

// ---------------------------------------------------------------------------
// 3. kNN within radius: one wave per query, stable (d2, idx) ascending, K=34.
// ---------------------------------------------------------------------------
__global__ void knn_kernel(const float* __restrict__ coord, int* __restrict__ nbr) {
    __shared__ float sx[NPTQ], sy[NPTQ], sz[NPTQ];
    const double RAD2D = (2.5 * 0.04) * (2.5 * 0.04);
    int b = blockIdx.x >> 8;              // 256 blocks per batch
    int i0 = (blockIdx.x & 255) * 4;
    const float* cb = coord + (size_t)b * NPTQ * 3;
    for (int t = threadIdx.x; t < NPTQ; t += 256) {
        sx[t] = cb[(size_t)t * 3 + 0];
        sy[t] = cb[(size_t)t * 3 + 1];
        sz[t] = cb[(size_t)t * 3 + 2];
    }
    __syncthreads();
    int wid = threadIdx.x >> 6, lane = threadIdx.x & 63;
    int i = i0 + wid;
    float qx = sx[i], qy = sy[i], qz = sz[i];
    u64 pk[16];
#pragma unroll
    for (int t = 0; t < 16; ++t) {
        int j = lane + t * 64;
        float dx = __fsub_rn(qx, sx[j]);
        float dy = __fsub_rn(qy, sy[j]);
        float dz = __fsub_rn(qz, sz[j]);
        float d2 = __fadd_rn(__fadd_rn(__fmul_rn(dx, dx), __fmul_rn(dy, dy)),
                             __fmul_rn(dz, dz));
        bool valid = ((double)d2 <= RAD2D);
        pk[t] = valid ? (((u64)__float_as_uint(d2) << 32) | (u32)j) : ~0ull;
    }
    int* out = nbr + ((size_t)b * NPTQ + i) * KNB;
    int k = 0;
    for (; k < KNB; ++k) {
        u64 m = ~0ull;
#pragma unroll
        for (int t = 0; t < 16; ++t) m = (pk[t] < m) ? pk[t] : m;
#pragma unroll
        for (int s = 32; s; s >>= 1) {
            u64 o = __shfl_xor(m, s, 64);
            m = (o < m) ? o : m;
        }
        if (m == ~0ull) break;
#pragma unroll
        for (int t = 0; t < 16; ++t) if (pk[t] == m) pk[t] = ~0ull;
        if (lane == 0) out[k] = (int)(m & 0xFFFFFFFFu);
    }
    for (; k < KNB; ++k) if (lane == 0) out[k] = -1;
}

// ---------------------------------------------------------------------------
// 4. x = [color, coord] @ W_in + b_in  (reads inputs directly via fps_idx/sel)
// ---------------------------------------------------------------------------
__global__ void xproj_kernel(const float* __restrict__ pc, const float* __restrict__ col,
                             const int* __restrict__ fps_idx, const int* __restrict__ sel,
                             const float* __restrict__ Win, const float* __restrict__ bin,
                             float* __restrict__ x) {
    int idx = blockIdx.x * 256 + threadIdx.x;
    if (idx >= NQ * CH) return;
    int q = idx / CH, c = idx - q * CH;
    int b = q >> 10, j = q & 1023;
    int p = fps_idx[b * NALL + sel[j]];
    p = (p < 0) ? 0 : ((p >= NIN) ? (NIN - 1) : p);
    const float* pp = pc + ((size_t)b * NIN + p) * 3;
    const float* cc = col + ((size_t)b * NIN + p) * 3;
    float acc = bin[c];
    acc += cc[0] * Win[0 * CH + c];
    acc += cc[1] * Win[1 * CH + c];
    acc += cc[2] * Win[2 * CH + c];
    acc += pp[0] * Win[3 * CH + c];
    acc += pp[1] * Win[4 * CH + c];
    acc += pp[2] * Win[5 * CH + c];
    x[idx] = acc;
}

// ---------------------------------------------------------------------------
// 5. q,k,v = x @ Wq/Wk/Wv  (computed once per point)
// ---------------------------------------------------------------------------
__global__ void qkv_kernel(const float* __restrict__ x,
                           const float* __restrict__ Wq, const float* __restrict__ Wk,
                           const float* __restrict__ Wv,
                           float* __restrict__ qo, float* __restrict__ ko,
                           float* __restrict__ vo) {
    int idx = blockIdx.x * 256 + threadIdx.x;
    if (idx >= NQ * CH) return;
    int q = idx / CH, c = idx - q * CH;
    const float* xr = x + (size_t)q * CH;
    float aq = 0.f, ak = 0.f, av = 0.f;
    for (int k = 0; k < CH; ++k) {
        float xv = xr[k];
        aq += xv * Wq[k * CH + c];
        ak += xv * Wk[k * CH + c];
        av += xv * Wv[k * CH + c];
    }
    qo[idx] = aq; ko[idx] = ak; vo[idx] = av;
}

// ---------------------------------------------------------------------------
// 6. Attention (online softmax) fused with o-projection + residual.
//    Block = 384 threads = 4 queries x 96 channels; r1 in-place over q.
// ---------------------------------------------------------------------------
__global__ __launch_bounds__(384) void attn_kernel(float* __restrict__ qr1,
                            const float* __restrict__ km, const float* __restrict__ vm,
                            const float* __restrict__ coord, const int* __restrict__ nbr,
                            const float* __restrict__ Wpos, const float* __restrict__ Wo,
                            const float* __restrict__ x) {
    __shared__ float wp[3 * CH];
    __shared__ float os[4][CH];
    for (int t = threadIdx.x; t < 3 * CH; t += 384) wp[t] = Wpos[t];
    __syncthreads();
    int lq = threadIdx.x / CH;
    int c = threadIdx.x - lq * CH;
    int qi = blockIdx.x * 4 + lq;           // global row 0..8191
    int b = qi >> 10, i = qi & 1023;
    const float* crd = coord + (size_t)b * NPTQ * 3;
    float cx = crd[(size_t)i * 3], cy = crd[(size_t)i * 3 + 1], cz = crd[(size_t)i * 3 + 2];
    float qv = qr1[(size_t)qi * CH + c];
    const int* nb = nbr + (size_t)qi * KNB;
    float m = -1e30f, l = 0.f, acc = 0.f;
    for (int t = 0; t < KNB; ++t) {
        int j = nb[t];                      // uniform across the row's 96 threads
        if (j < 0) break;                   // valid-first ordering
        float dx = cx - crd[(size_t)j * 3];
        float dy = cy - crd[(size_t)j * 3 + 1];
        float dz = cz - crd[(size_t)j * 3 + 2];
        float pe = dx * wp[c] + dy * wp[CH + c] + dz * wp[2 * CH + c];
        size_t row = (size_t)(b * NPTQ + j) * CH + c;
        float kn = km[row] + pe;
        float s = qv * kn;
        s += __shfl_xor(s, 1); s += __shfl_xor(s, 2);
        s += __shfl_xor(s, 4); s += __shfl_xor(s, 8);
        float logit = s * 0.25f;            // / sqrt(16)
        float mn = fmaxf(m, logit);
        float sc = expf(m - mn);
        float p = expf(logit - mn);
        float vn = vm[row] + pe;
        l = l * sc + p;
        acc = acc * sc + p * vn;
        m = mn;
    }
    os[lq][c] = (l > 0.f) ? acc / l : 0.f;  // self is always valid -> l >= 1
    __syncthreads();
    // r1 = x + attn_out @ Wo
    float r = x[(size_t)qi * CH + c];
    for (int k = 0; k < CH; ++k) r += os[lq][k] * Wo[k * CH + c];
    qr1[(size_t)qi * CH + c] = r;
}

// ---------------------------------------------------------------------------
// 7. LayerNorm (wave per row of 96)
// ---------------------------------------------------------------------------
__global__ void ln_kernel(const float* __restrict__ in, const float* __restrict__ g,
                          const float* __restrict__ be, float* __restrict__ out) {
    int row = blockIdx.x * 4 + (threadIdx.x >> 6);
    int lane = threadIdx.x & 63;
    const float* r = in + (size_t)row * CH;
    float e0 = r[lane];
    float e1 = (lane < 32) ? r[64 + lane] : 0.0f;
    float s = e0 + e1;
#pragma unroll
    for (int k = 32; k; k >>= 1) s += __shfl_xor(s, k);
    float mean = s * (1.0f / 96.0f);
    float d0 = e0 - mean, d1 = e1 - mean;
    float vs = d0 * d0 + ((lane < 32) ? d1 * d1 : 0.0f);
#pragma unroll
    for (int k = 32; k; k >>= 1) vs += __shfl_xor(vs, k);
    float rs = 1.0f / sqrtf(vs * (1.0f / 96.0f) + 1e-5f);
    float* o = out + (size_t)row * CH;
    o[lane] = d0 * rs * g[lane] + be[lane];
    if (lane < 32) o[64 + lane] = d1 * rs * g[64 + lane] + be[64 + lane];
}

// ---------------------------------------------------------------------------
// 8. Fused FFN, 4 rows per block (weight traffic /4):
//    r2 = x2 + relu(x2 @ W1 + b1) @ W2 + b2
// ---------------------------------------------------------------------------
__global__ __launch_bounds__(384) void ffn_kernel(const float* __restrict__ x2,
                           const float* __restrict__ W1, const float* __restrict__ b1,
                           const float* __restrict__ W2, const float* __restrict__ b2,
                           float* __restrict__ r2) {
    __shared__ float xs[4][CH];
    __shared__ float hs[4][FF];
    __shared__ float ps[4][4][CH];
    int row0 = blockIdx.x * 4, t = threadIdx.x;
    { int r = t / CH, c = t - (t / CH) * CH;
      xs[r][c] = x2[(size_t)(row0 + r) * CH + c]; }
    __syncthreads();
    {
        float bt = b1[t];
        float a0 = bt, a1 = bt, a2 = bt, a3 = bt;
        for (int k = 0; k < CH; ++k) {
            float w = W1[k * FF + t];
            a0 += xs[0][k] * w; a1 += xs[1][k] * w;
            a2 += xs[2][k] * w; a3 += xs[3][k] * w;
        }
        hs[0][t] = fmaxf(a0, 0.f); hs[1][t] = fmaxf(a1, 0.f);
        hs[2][t] = fmaxf(a2, 0.f); hs[3][t] = fmaxf(a3, 0.f);
    }
    __syncthreads();
    {
        int chunk = t / CH, c = t - (t / CH) * CH;
        float p0 = 0.f, p1 = 0.f, p2 = 0.f, p3 = 0.f;
        for (int m = chunk * CH; m < (chunk + 1) * CH; ++m) {
            float w = W2[m * CH + c];
            p0 += hs[0][m] * w; p1 += hs[1][m] * w;
            p2 += hs[2][m] * w; p3 += hs[3][m] * w;
        }
        ps[0][chunk][c] = p0; ps[1][chunk][c] = p1;
        ps[2][chunk][c] = p2; ps[3][chunk][c] = p3;
    }
    __syncthreads();
    { int r = t / CH, c = t - (t / CH) * CH;
      float rr = xs[r][c] + ((ps[r][0][c] + ps[r][1][c]) + (ps[r][2][c] + ps[r][3][c])) + b2[c];
      r2[(size_t)(row0 + r) * CH + c] = rr; }
}

// ---------------------------------------------------------------------------
// 9. LN2 + transposed fp32 store: out[b][c][i] = LN(r2)[b][i][c]
// ---------------------------------------------------------------------------
__global__ void ln2t_kernel(const float* __restrict__ in, const float* __restrict__ g,
                            const float* __restrict__ be, float* __restrict__ out) {
    int row = blockIdx.x * 4 + (threadIdx.x >> 6);
    int lane = threadIdx.x & 63;
    int b = row >> 10, i = row & 1023;
    const float* r = in + (size_t)row * CH;
    float e0 = r[lane];
    float e1 = (lane < 32) ? r[64 + lane] : 0.0f;
    float s = e0 + e1;
#pragma unroll
    for (int k = 32; k; k >>= 1) s += __shfl_xor(s, k);
    float mean = s * (1.0f / 96.0f);
    float d0 = e0 - mean, d1 = e1 - mean;
    float vs = d0 * d0 + ((lane < 32) ? d1 * d1 : 0.0f);
#pragma unroll
    for (int k = 32; k; k >>= 1) vs += __shfl_xor(vs, k);
    float rs = 1.0f / sqrtf(vs * (1.0f / 96.0f) + 1e-5f);
    float y0 = d0 * rs * g[lane] + be[lane];
    out[((size_t)(b * CH + lane)) * NPTQ + i] = scrub(y0);
    if (lane < 32) {
        float y1 = d1 * rs * g[64 + lane] + be[64 + lane];
        out[((size_t)(b * CH + 64 + lane)) * NPTQ + i] = scrub(y1);
    }
}

// ---------------------------------------------------------------------------
extern "C" void kernel_launch(void* const* d_in, const int* in_sizes, int n_in,
                              void* d_out, int out_size, void* d_ws, size_t ws_size,
                              hipStream_t stream) {
    const float* pc   = (const float*)d_in[0];
    const float* col  = (const float*)d_in[1];
    const float* Win  = (const float*)d_in[2];
    const float* bin  = (const float*)d_in[3];
    const float* Wq   = (const float*)d_in[4];
    const float* Wk   = (const float*)d_in[5];
    const float* Wv   = (const float*)d_in[6];
    const float* Wo   = (const float*)d_in[7];
    const float* Wpos = (const float*)d_in[8];
    const float* W1   = (const float*)d_in[9];
    const float* b1   = (const float*)d_in[10];
    const float* W2   = (const float*)d_in[11];
    const float* b2   = (const float*)d_in[12];
    const float* g1   = (const float*)d_in[13];
    const float* be1  = (const float*)d_in[14];
    const float* g2   = (const float*)d_in[15];
    const float* be2  = (const float*)d_in[16];
    const int*  sel   = (const int*)d_in[17];

    float* out_feat  = (float*)d_out;                      // 8*96*1024 fp32
    float* out_coord = out_feat + (size_t)B_ * CH * NPTQ;  // 8*1024*3 fp32

    // Workspace: ~13.8 MB total.
    char* ws = (char*)d_ws;
    size_t off = 0;
    auto alloc = [&](size_t bytes) { void* p = ws + off; off += (bytes + 255) & ~(size_t)255; return p; };
    int*   w_fps   = (int*)  alloc((size_t)B_ * NALL * 4);       //  38 KB
    float* w_coord = (float*)alloc((size_t)NQ * 3 * 4);          //  98 KB
    int*   w_nbr   = (int*)  alloc((size_t)NQ * KNB * 4);        // 1.1 MB
    float* w_x     = (float*)alloc((size_t)NQ * CH * 4);         // 3.1 MB
    float* w_q     = (float*)alloc((size_t)NQ * CH * 4);         // 3.1 MB (q -> r1 in-place)
    float* w_k     = (float*)alloc((size_t)NQ * CH * 4);         // 3.1 MB (k -> x2 after attn)
    float* w_v     = (float*)alloc((size_t)NQ * CH * 4);         // 3.1 MB (v -> r2 after attn)
    (void)ws_size; (void)in_sizes; (void)n_in; (void)out_size;

    fps_kernel<<<B_, FT, 0, stream>>>(pc, w_fps);
    gather_kernel<<<NQ / 256, 256, 0, stream>>>(pc, w_fps, sel, w_coord, out_coord);
    knn_kernel<<<NQ / 4, 256, 0, stream>>>(w_coord, w_nbr);
    xproj_kernel<<<NQ * CH / 256, 256, 0, stream>>>(pc, col, w_fps, sel, Win, bin, w_x);
    qkv_kernel<<<NQ * CH / 256, 256, 0, stream>>>(w_x, Wq, Wk, Wv, w_q, w_k, w_v);
    attn_kernel<<<NQ / 4, 384, 0, stream>>>(w_q, w_k, w_v, w_coord, w_nbr, Wpos, Wo, w_x);
    ln_kernel<<<NQ / 4, 256, 0, stream>>>(w_q, g1, be1, w_k);       // r1 -> x2
    ffn_kernel<<<NQ / 4, 384, 0, stream>>>(w_k, W1, b1, W2, b2, w_v);   // x2 -> r2
    ln2t_kernel<<<NQ / 4, 256, 0, stream>>>(w_v, g2, be2, out_feat);
}